// Round 12
// baseline (8941.179 us; speedup 1.0000x reference)
//
#include <hip/hip_runtime.h>
#include <hip/hip_bf16.h>
#include <stdint.h>

#define VOCAB 32000
#define HIDDEN 512
#define TSEQ 1024

typedef __attribute__((ext_vector_type(4))) float f32x4;
typedef __attribute__((ext_vector_type(8))) short short8;
typedef __attribute__((ext_vector_type(2))) unsigned uint2v;

union bfpack8 { short8 s; __hip_bfloat16 e[8]; };

// MFMA with A-operand pinned in AGPRs ("a" constraint) — the arch-VGPR file
// (v0..v255) cannot hold the weights, but the AGPR file (a0..a255) can, and
// v_mfma reads SrcA from AGPRs natively (cdna4_isa §10). Compiler never does
// this on its own (R3/R6/R8/R10 all streamed weights instead).
#define MFMA_A(acc, afrag, bfrag) \
  asm("v_mfma_f32_16x16x32_bf16 %0, %1, %2, %0" : "+v"(acc) : "a"(afrag), "v"(bfrag))
#define MFMA_V(acc, afrag, bfrag) \
  asm("v_mfma_f32_16x16x32_bf16 %0, %1, %2, %0" : "+v"(acc) : "v"(afrag), "v"(bfrag))

// ---------------- kernel: f32 -> bf16 convert (Why_w) ----------------
__global__ __launch_bounds__(256) void k_convert(const float* __restrict__ in,
                                                 __hip_bfloat16* __restrict__ out,
                                                 int n4) {
  int stride = gridDim.x * blockDim.x;
  for (int i = blockIdx.x * blockDim.x + threadIdx.x; i < n4; i += stride) {
    const float4 v = *reinterpret_cast<const float4*>(in + (size_t)i * 4);
    union { __hip_bfloat16 h[4]; ushort4 u; } p;
    p.h[0] = __float2bfloat16(v.x);
    p.h[1] = __float2bfloat16(v.y);
    p.h[2] = __float2bfloat16(v.z);
    p.h[3] = __float2bfloat16(v.w);
    *reinterpret_cast<ushort4*>(out + (size_t)i * 4) = p.u;
  }
}

// ---- pre[t][j] = Wxh_w[j][idx[t]] + Wxh_b[j] + Whh_b[j] ----
__global__ __launch_bounds__(512) void k_pre(const int* __restrict__ idx,
                                             const float* __restrict__ Wxh_w,
                                             const float* __restrict__ Wxh_b,
                                             const float* __restrict__ Whh_b,
                                             float* __restrict__ pre) {
  const int t = blockIdx.x;
  const int j = threadIdx.x;
  const int c = idx[t];
  pre[(size_t)t * HIDDEN + j] = Wxh_w[(size_t)j * VOCAB + c] + Wxh_b[j] + Whh_b[j];
}

// ---------------- kernel: sequential scan — ONE workgroup, ONE CU ----------------
// 1024 threads = 16 waves. Wave w owns rows [32w, 32w+32) of Whh as hi+lo bf16
// MFMA A-fragments: chunks 0..14 in AGPRs (240 a-regs, "a" constraint), chunk 15
// in VGPRs. h lives in a 2KB LDS double buffer; the ONLY sync is __syncthreads.
// No cross-WG protocol, no sc0/sc1, no sentinels, no placement assumptions —
// the failure classes of R4/R5/R9/R11 are structurally impossible here.
// Per step per wave: 16 broadcast ds_read_b128 + 64 MFMA + tanh + 1 barrier.
__global__ __launch_bounds__(1024, 4) void k_scan(const float* __restrict__ pre,
                                                  const float* __restrict__ Whh,
                                                  const float* __restrict__ h0,
                                                  __hip_bfloat16* __restrict__ h_seq,
                                                  float* __restrict__ h_final) {
  __shared__ __align__(16) __hip_bfloat16 hbuf[2][HIDDEN];

  const int tid = threadIdx.x;
  const int w = tid >> 6;     // wave 0..15
  const int l = tid & 63;
  const int l15 = l & 15;
  const int l4 = l >> 4;
  const int base = w * 32;    // this wave's 32 rows

  // one-time: A-fragments, split precision W ~= hi(bf16) + lo(bf16).
  // Fragment (tile tl, chunk kk): lane l holds W[base+tl*16+l15][kk*32+l4*8 .. +8]
  short8 ah[2][16], al[2][16];
#pragma unroll
  for (int tl = 0; tl < 2; ++tl) {
    const float* wp = Whh + (size_t)(base + tl * 16 + l15) * HIDDEN + l4 * 8;
#pragma unroll
    for (int kk = 0; kk < 16; ++kk) {
      const f32x4 a = *reinterpret_cast<const f32x4*>(wp + kk * 32);
      const f32x4 b = *reinterpret_cast<const f32x4*>(wp + kk * 32 + 4);
      bfpack8 hi, lo;
#pragma unroll
      for (int i = 0; i < 4; ++i) {
        hi.e[i] = __float2bfloat16(a[i]);
        lo.e[i] = __float2bfloat16(a[i] - __bfloat162float(hi.e[i]));
        hi.e[4 + i] = __float2bfloat16(b[i]);
        lo.e[4 + i] = __float2bfloat16(b[i] - __bfloat162float(hi.e[4 + i]));
      }
      ah[tl][kk] = hi.s;
      al[tl][kk] = lo.s;
    }
  }

  if (tid < HIDDEN) hbuf[0][tid] = __float2bfloat16(h0[tid]);
  __syncthreads();

  for (int t = 1; t <= TSEQ; ++t) {
    // additive term for this wave's 8 output rows (2 tiles x 4), h-independent
    const float* pp = pre + (size_t)(t - 1) * HIDDEN + base + l4 * 4;
    const f32x4 pv0 = *reinterpret_cast<const f32x4*>(pp);
    const f32x4 pv1 = *reinterpret_cast<const f32x4*>(pp + 16);

    // B fragments: broadcast LDS reads; lane l needs h[kk*32 + l4*8 .. +8]
    const __hip_bfloat16* hrd = hbuf[(t - 1) & 1];
    short8 bq[16];
#pragma unroll
    for (int kk = 0; kk < 16; ++kk)
      bq[kk] = *reinterpret_cast<const short8*>(hrd + kk * 32 + l4 * 8);

    f32x4 acc0 = {0.f, 0.f, 0.f, 0.f};
    f32x4 acc1 = {0.f, 0.f, 0.f, 0.f};
    f32x4 acc2 = {0.f, 0.f, 0.f, 0.f};
    f32x4 acc3 = {0.f, 0.f, 0.f, 0.f};
#pragma unroll
    for (int kk = 0; kk < 15; ++kk) {
      MFMA_A(acc0, ah[0][kk], bq[kk]);
      MFMA_A(acc1, ah[1][kk], bq[kk]);
      MFMA_A(acc2, al[0][kk], bq[kk]);
      MFMA_A(acc3, al[1][kk], bq[kk]);
    }
    MFMA_V(acc0, ah[0][15], bq[15]);
    MFMA_V(acc1, ah[1][15], bq[15]);
    MFMA_V(acc2, al[0][15], bq[15]);
    MFMA_V(acc3, al[1][15], bq[15]);
    // MFMA->VALU RAW hazard: compiler can't see into the asm, so it won't insert
    // the required wait states. Fence with register-tied s_nops (data-dep ordered).
    asm volatile("s_nop 7\n\ts_nop 7\n\ts_nop 7"
                 : "+v"(acc0), "+v"(acc1), "+v"(acc2), "+v"(acc3));
    const f32x4 s0 = acc0 + acc2;
    const f32x4 s1 = acc1 + acc3;

    // h_new = tanh(pre + acc); rows base + tl*16 + l4*4 + q (cols redundant x16)
    float y0[4], y1[4];
#pragma unroll
    for (int q = 0; q < 4; ++q) {
      const float x0 = fminf(fmaxf(pv0[q] + s0[q], -15.f), 15.f);
      const float e0 = __expf(2.f * x0);
      y0[q] = (e0 - 1.f) * __builtin_amdgcn_rcpf(e0 + 1.f);
      const float x1 = fminf(fmaxf(pv1[q] + s1[q], -15.f), 15.f);
      const float e1 = __expf(2.f * x1);
      y1[q] = (e1 - 1.f) * __builtin_amdgcn_rcpf(e1 + 1.f);
    }

    __hip_bfloat16* hwr = hbuf[t & 1];
    if (l15 == 0) {  // lanes l4=0..3 publish 4 rows per tile (8B packed)
      union { uint2v u; __hip_bfloat16 e[4]; } p0, p1;
#pragma unroll
      for (int q = 0; q < 4; ++q) {
        p0.e[q] = __float2bfloat16(y0[q]);
        p1.e[q] = __float2bfloat16(y1[q]);
      }
      *reinterpret_cast<uint2v*>(hwr + base + l4 * 4) = p0.u;
      *reinterpret_cast<uint2v*>(hwr + base + 16 + l4 * 4) = p1.u;
      __hip_bfloat16* hs = h_seq + (size_t)(t - 1) * HIDDEN + base + l4 * 4;
      *reinterpret_cast<uint2v*>(hs) = p0.u;       // for the logits GEMM
      *reinterpret_cast<uint2v*>(hs + 16) = p1.u;
      if (t == TSEQ) {
        const f32x4 f0 = {y0[0], y0[1], y0[2], y0[3]};
        const f32x4 f1 = {y1[0], y1[1], y1[2], y1[3]};
        *reinterpret_cast<f32x4*>(h_final + base + l4 * 4) = f0;
        *reinterpret_cast<f32x4*>(h_final + base + 16 + l4 * 4) = f1;
      }
    }
    __syncthreads();  // hwr visible to all waves; hrd free for overwrite
  }
}

// ---------------- kernel: logits = h_seq @ Why_w^T + bias (bf16 MFMA) ----------------
__global__ __launch_bounds__(256) void k_gemm(const __hip_bfloat16* __restrict__ A,
                                              const __hip_bfloat16* __restrict__ B,
                                              const float* __restrict__ bias,
                                              float* __restrict__ C) {
  __shared__ __hip_bfloat16 As[128][32];
  __shared__ __hip_bfloat16 Bs[128][32];
  const int bn = blockIdx.x;  // 0..249
  const int bm = blockIdx.y;  // 0..7
  const int tid = threadIdx.x;
  const int lane = tid & 63;
  const int wid = tid >> 6;
  const int wr = (wid >> 1) * 64;
  const int wc = (wid & 1) * 64;
  const int l15 = lane & 15;
  const int kc = lane >> 4;

  const int sr = tid >> 1;        // staging row 0..127
  const int sc = (tid & 1) * 16;  // staging k offset {0,16}

  const __hip_bfloat16* Ag = A + (size_t)(bm * 128 + sr) * HIDDEN + sc;
  const __hip_bfloat16* Bg = B + (size_t)(bn * 128 + sr) * HIDDEN + sc;

  f32x4 acc[4][4];
#pragma unroll
  for (int m = 0; m < 4; ++m)
#pragma unroll
    for (int n = 0; n < 4; ++n) {
      acc[m][n][0] = 0.f; acc[m][n][1] = 0.f; acc[m][n][2] = 0.f; acc[m][n][3] = 0.f;
    }

  for (int ks = 0; ks < HIDDEN; ks += 32) {
    __syncthreads();  // WAR: previous iteration's reads done
    *reinterpret_cast<short8*>(&As[sr][sc])     = *reinterpret_cast<const short8*>(Ag + ks);
    *reinterpret_cast<short8*>(&As[sr][sc + 8]) = *reinterpret_cast<const short8*>(Ag + ks + 8);
    *reinterpret_cast<short8*>(&Bs[sr][sc])     = *reinterpret_cast<const short8*>(Bg + ks);
    *reinterpret_cast<short8*>(&Bs[sr][sc + 8]) = *reinterpret_cast<const short8*>(Bg + ks + 8);
    __syncthreads();

    short8 af[4], bfr[4];
#pragma unroll
    for (int m = 0; m < 4; ++m)
      af[m] = *reinterpret_cast<const short8*>(&As[wr + m * 16 + l15][kc * 8]);
#pragma unroll
    for (int n = 0; n < 4; ++n)
      bfr[n] = *reinterpret_cast<const short8*>(&Bs[wc + n * 16 + l15][kc * 8]);
#pragma unroll
    for (int m = 0; m < 4; ++m)
#pragma unroll
      for (int n = 0; n < 4; ++n)
        acc[m][n] = __builtin_amdgcn_mfma_f32_16x16x32_bf16(af[m], bfr[n], acc[m][n], 0, 0, 0);
  }

  // epilogue: C/D layout col = lane&15, row = (lane>>4)*4 + q
#pragma unroll
  for (int m = 0; m < 4; ++m) {
#pragma unroll
    for (int n = 0; n < 4; ++n) {
      const int vcol = bn * 128 + wc + n * 16 + l15;
      const float bv = bias[vcol];
#pragma unroll
      for (int q = 0; q < 4; ++q) {
        const int trow = bm * 128 + wr + m * 16 + kc * 4 + q;
        C[(size_t)trow * VOCAB + vcol] = acc[m][n][q] + bv;
      }
    }
  }
}

extern "C" void kernel_launch(void* const* d_in, const int* in_sizes, int n_in,
                              void* d_out, int out_size, void* d_ws, size_t ws_size,
                              hipStream_t stream) {
  (void)in_sizes; (void)n_in; (void)out_size; (void)ws_size;

  const int*   idx   = (const int*)d_in[0];
  const float* h0    = (const float*)d_in[1];
  const float* Wxh_w = (const float*)d_in[2];
  const float* Wxh_b = (const float*)d_in[3];
  const float* Whh_w = (const float*)d_in[4];
  const float* Whh_b = (const float*)d_in[5];
  const float* Why_w = (const float*)d_in[6];
  const float* Why_b = (const float*)d_in[7];
  float* out = (float*)d_out;

  // workspace layout (bytes)
  char* ws = (char*)d_ws;
  __hip_bfloat16* why_bf = (__hip_bfloat16*)(ws);                     // 32,768,000
  float* pre = (float*)(ws + 32768000);                               // 2,097,152
  __hip_bfloat16* h_seq = (__hip_bfloat16*)(ws + 34865152);           // 1,048,576

  k_convert<<<2048, 256, 0, stream>>>(Why_w, why_bf, (VOCAB * HIDDEN) / 4);
  k_pre<<<TSEQ, HIDDEN, 0, stream>>>(idx, Wxh_w, Wxh_b, Whh_b, pre);
  k_scan<<<1, 1024, 0, stream>>>(pre, Whh_w, h0, h_seq, out + 32768000);
  k_gemm<<<dim3(VOCAB / 128, TSEQ / 128), 256, 0, stream>>>(h_seq, why_bf, Why_b, out);
}

// Round 15
// 1469.396 us; speedup vs baseline: 6.0849x; 6.0849x over previous
//
#include <hip/hip_runtime.h>
#include <hip/hip_bf16.h>
#include <stdint.h>

#define VOCAB 32000
#define HIDDEN 512
#define TSEQ 1024
#define SENT 0x7F807F80u   // two +inf bf16 — unrepresentable in tanh/h0 data
#define NSCANBLK 32        // blocks 0..31: wave 0 scans 16 rows each
#define NBLK 256           // 1 block/CU, fully co-resident
#define NGEMMBLK (NBLK - NSCANBLK)
#define NTILE 2000         // 8 bm x 250 bn

typedef __attribute__((ext_vector_type(4))) float f32x4;
typedef __attribute__((ext_vector_type(8))) short short8;
typedef __attribute__((ext_vector_type(2))) unsigned uint2v;

union bfpack8 { short8 s; __hip_bfloat16 e[8]; };
union frag_u { short8 s; uint4 u; };

// ---------------- kernel: fill h rows 1..TSEQ with the sentinel ----------------
__global__ __launch_bounds__(256) void k_fill(uint4* __restrict__ p, int n4) {
  const int i = blockIdx.x * blockDim.x + threadIdx.x;
  if (i < n4) {
    uint4 v; v.x = SENT; v.y = SENT; v.z = SENT; v.w = SENT;
    p[i] = v;
  }
}

// ---- pre[t][j] = Wxh_w[j][idx[t]] + Wxh_b[j] + Whh_b[j];  h_bf[0] = bf16(h0) ----
__global__ __launch_bounds__(512) void k_pre(const int* __restrict__ idx,
                                             const float* __restrict__ h0,
                                             const float* __restrict__ Wxh_w,
                                             const float* __restrict__ Wxh_b,
                                             const float* __restrict__ Whh_b,
                                             float* __restrict__ pre,
                                             __hip_bfloat16* __restrict__ h_bf) {
  const int t = blockIdx.x;
  const int j = threadIdx.x;
  const int c = idx[t];
  pre[(size_t)t * HIDDEN + j] = Wxh_w[(size_t)j * VOCAB + c] + Wxh_b[j] + Whh_b[j];
  if (t == 0) h_bf[j] = __float2bfloat16(h0[j]);  // finite => never SENT
}

// device-coherent 16B load with intrinsic sentinel retry. Load + waitcnt live in
// ONE asm block — the ONLY proven-safe construct (R9/R13/R14: any detached
// in-flight load is corrupted by regalloc copy/spill placement).
__device__ __forceinline__ short8 poll16(const void* p) {
  short8 v;
  for (;;) {
    asm volatile("global_load_dwordx4 %0, %1, off sc0 sc1\n\ts_waitcnt vmcnt(0)"
                 : "=v"(v) : "v"(p));
    frag_u f; f.s = v;
    if ((f.u.x != SENT) & (f.u.y != SENT) & (f.u.z != SENT) & (f.u.w != SENT))
      return v;
  }
}

// ---------------- fused kernel: scan (blocks 0..31) + persistent GEMM ----------------
// Scan path: R8's proven protocol VERBATIM (1414 us measured) — single-wave
//   participants, weights as hi+lo bf16 fragments in a 32KB LDS carve, sentinel
//   handoff through the memory-side coherent point with single-asm-block polls.
// GEMM path: persistent tiles gated on h-row availability (skew <= 1 step =>
//   any dword of row bm*128+129 non-sentinel implies rows <= bm*128+128 done);
//   poll16 A-staging is the correctness backstop; B converts f32->bf16 in
//   staging registers (k_convert deleted, its cost hidden under the scan).
__global__ __launch_bounds__(256, 1) void k_fused(
    const float* __restrict__ pre, const float* __restrict__ Whh,
    __hip_bfloat16* __restrict__ h_bf, float* __restrict__ h_final,
    const float* __restrict__ Why_w, const float* __restrict__ Why_b,
    float* __restrict__ C) {
  __shared__ __align__(16) char sh[33792];  // union: scan 32KB+1KB | gemm 8KB+8KB

  const int blk = blockIdx.x;
  const int tid = threadIdx.x;

  if (blk < NSCANBLK) {
    // ===================== scan path (R8 verbatim, wave 0 only) =====================
    if (tid >= 64) return;
    short8 (*afrag)[64] = reinterpret_cast<short8 (*)[64]>(sh);          // 32 KB
    __hip_bfloat16* hstage = reinterpret_cast<__hip_bfloat16*>(sh + 32768);  // 1 KB

    const int wv = blk;
    const int l = tid;
    const int l15 = l & 15;
    const int l4 = l >> 4;
    const int base = wv * 16;

    // one-time: build A-fragments (W ~= hi(bf16) + lo(bf16)), stash in LDS
    {
      const float* wp = Whh + (size_t)(base + l15) * HIDDEN + l4 * 8;
#pragma unroll
      for (int kk = 0; kk < 16; ++kk) {
        const f32x4 a = *reinterpret_cast<const f32x4*>(wp + kk * 32);
        const f32x4 b = *reinterpret_cast<const f32x4*>(wp + kk * 32 + 4);
        bfpack8 hi, lo;
#pragma unroll
        for (int i = 0; i < 4; ++i) {
          hi.e[i] = __float2bfloat16(a[i]);
          lo.e[i] = __float2bfloat16(a[i] - __bfloat162float(hi.e[i]));
          hi.e[4 + i] = __float2bfloat16(b[i]);
          lo.e[4 + i] = __float2bfloat16(b[i] - __bfloat162float(hi.e[4 + i]));
        }
        afrag[2 * kk][l] = hi.s;
        afrag[2 * kk + 1][l] = lo.s;
      }
    }
    // single wave: LDS producer==consumer; compiler orders via lgkmcnt

    for (int t = 1; t <= TSEQ; ++t) {
      const float* pp = pre + (size_t)(t - 1) * HIDDEN + base + l4 * 4;
      const f32x4 pv = *reinterpret_cast<const f32x4*>(pp);

      // coalesced sentinel poll: lane l owns bytes [16l,16l+16) of row t-1
      const __hip_bfloat16* hrow = h_bf + (size_t)(t - 1) * HIDDEN + l * 8;
      short8 hv;
      unsigned ok;
      do {
        asm volatile("global_load_dwordx4 %0, %1, off sc0 sc1\n\ts_waitcnt vmcnt(0)"
                     : "=&v"(hv) : "v"(hrow) : "memory");
        frag_u f; f.s = hv;
        ok = (unsigned)(f.u.x != SENT) & (unsigned)(f.u.y != SENT) &
             (unsigned)(f.u.z != SENT) & (unsigned)(f.u.w != SENT);
      } while (!__all(ok != 0u));

      // LDS bounce: coalesced layout -> B-fragment layout
      *reinterpret_cast<short8*>(&hstage[l * 8]) = hv;  // ds_write_b128
      short8 bq[16];
#pragma unroll
      for (int kk = 0; kk < 16; ++kk)
        bq[kk] = *reinterpret_cast<const short8*>(&hstage[kk * 32 + l4 * 8]);

      f32x4 acc0 = {0.f, 0.f, 0.f, 0.f};
      f32x4 acc1 = {0.f, 0.f, 0.f, 0.f};
      f32x4 acc2 = {0.f, 0.f, 0.f, 0.f};
      f32x4 acc3 = {0.f, 0.f, 0.f, 0.f};
#pragma unroll
      for (int kk = 0; kk < 8; ++kk) {
        acc0 = __builtin_amdgcn_mfma_f32_16x16x32_bf16(afrag[2 * kk][l], bq[kk], acc0, 0, 0, 0);
        acc2 = __builtin_amdgcn_mfma_f32_16x16x32_bf16(afrag[2 * kk + 1][l], bq[kk], acc2, 0, 0, 0);
        acc1 = __builtin_amdgcn_mfma_f32_16x16x32_bf16(afrag[2 * (kk + 8)][l], bq[kk + 8], acc1, 0, 0, 0);
        acc3 = __builtin_amdgcn_mfma_f32_16x16x32_bf16(afrag[2 * (kk + 8) + 1][l], bq[kk + 8], acc3, 0, 0, 0);
      }
      const f32x4 acc = (acc0 + acc1) + (acc2 + acc3);

      float y[4];
#pragma unroll
      for (int q = 0; q < 4; ++q) {
        const float x = fminf(fmaxf(pv[q] + acc[q], -15.f), 15.f);
        const float e = __expf(2.f * x);
        y[q] = (e - 1.f) * __builtin_amdgcn_rcpf(e + 1.f);
      }

      if (l15 == 0) {  // lanes l4=0..3 publish rows base + l4*4 + q (8B each)
        union { uint2v u; __hip_bfloat16 e[4]; } pk;
#pragma unroll
        for (int q = 0; q < 4; ++q) pk.e[q] = __float2bfloat16(y[q]);
        __hip_bfloat16* ha = h_bf + (size_t)t * HIDDEN + base + l4 * 4;
        asm volatile("global_store_dwordx2 %0, %1, off sc0 sc1"
                     :: "v"(ha), "v"(pk.u) : "memory");  // fire and forget
        if (t == TSEQ) {
          const f32x4 fo = {y[0], y[1], y[2], y[3]};
          *reinterpret_cast<f32x4*>(h_final + base + l4 * 4) = fo;
        }
      }
    }
    return;
  }

  // ===================== persistent GEMM path =====================
  __hip_bfloat16 (*As)[32] = reinterpret_cast<__hip_bfloat16 (*)[32]>(sh);         // 8 KB
  __hip_bfloat16 (*Bs)[32] = reinterpret_cast<__hip_bfloat16 (*)[32]>(sh + 8192);  // 8 KB

  const int lane = tid & 63;
  const int wid = tid >> 6;
  const int wr = (wid >> 1) * 64;
  const int wc = (wid & 1) * 64;
  const int l15g = lane & 15;
  const int kc = lane >> 4;
  const int sr = tid >> 1;
  const int sc = (tid & 1) * 16;
  const __hip_bfloat16* A = h_bf + HIDDEN;  // A row r = h after step r+1

  for (int tile = blk - NSCANBLK; tile < NTILE; tile += NGEMMBLK) {
    const int bm = tile / 250;
    const int bn = tile % 250;

    // gate: any dword of h_bf row min(bm*128+129, TSEQ) non-sentinel
    // => rows <= bm*128+128 fully visible (wave skew <= 1 step). bm=7 leans on
    // the poll16 staging backstop for the final rows.
    if (tid == 0) {
      const int sg = (bm * 128 + 129 < TSEQ) ? (bm * 128 + 129) : TSEQ;
      const unsigned* gp = reinterpret_cast<const unsigned*>(h_bf + (size_t)sg * HIDDEN);
      for (;;) {
        unsigned v;
        asm volatile("global_load_dword %0, %1, off sc0 sc1\n\ts_waitcnt vmcnt(0)"
                     : "=v"(v) : "v"(gp));
        if (v != SENT) break;
        asm volatile("s_sleep 16");
      }
    }
    __syncthreads();

    const __hip_bfloat16* Ag = A + (size_t)(bm * 128 + sr) * HIDDEN + sc;
    const float* BgF = Why_w + (size_t)(bn * 128 + sr) * HIDDEN + sc;

    f32x4 acc[4][4];
#pragma unroll
    for (int m = 0; m < 4; ++m)
#pragma unroll
      for (int n = 0; n < 4; ++n) {
        acc[m][n][0] = 0.f; acc[m][n][1] = 0.f; acc[m][n][2] = 0.f; acc[m][n][3] = 0.f;
      }

    for (int ks = 0; ks < HIDDEN; ks += 32) {
      __syncthreads();  // WAR on LDS
      // A staging: device-coherent sentinel-retry loads (backstop; rare post-gate)
      const short8 a0 = poll16(Ag + ks);
      const short8 a1 = poll16(Ag + ks + 8);
      *reinterpret_cast<short8*>(&As[sr][sc]) = a0;
      *reinterpret_cast<short8*>(&As[sr][sc + 8]) = a1;
      // B staging: f32 -> bf16 in-register conversion
      const float* bp = BgF + ks;
      const f32x4 x0 = *reinterpret_cast<const f32x4*>(bp);
      const f32x4 x1 = *reinterpret_cast<const f32x4*>(bp + 4);
      const f32x4 x2 = *reinterpret_cast<const f32x4*>(bp + 8);
      const f32x4 x3 = *reinterpret_cast<const f32x4*>(bp + 12);
      bfpack8 q0, q1;
#pragma unroll
      for (int i = 0; i < 4; ++i) {
        q0.e[i] = __float2bfloat16(x0[i]);
        q0.e[4 + i] = __float2bfloat16(x1[i]);
        q1.e[i] = __float2bfloat16(x2[i]);
        q1.e[4 + i] = __float2bfloat16(x3[i]);
      }
      *reinterpret_cast<short8*>(&Bs[sr][sc]) = q0.s;
      *reinterpret_cast<short8*>(&Bs[sr][sc + 8]) = q1.s;
      __syncthreads();

      short8 af[4], bfr[4];
#pragma unroll
      for (int m = 0; m < 4; ++m)
        af[m] = *reinterpret_cast<const short8*>(&As[wr + m * 16 + l15g][kc * 8]);
#pragma unroll
      for (int n = 0; n < 4; ++n)
        bfr[n] = *reinterpret_cast<const short8*>(&Bs[wc + n * 16 + l15g][kc * 8]);
#pragma unroll
      for (int m = 0; m < 4; ++m)
#pragma unroll
        for (int n = 0; n < 4; ++n)
          acc[m][n] = __builtin_amdgcn_mfma_f32_16x16x32_bf16(af[m], bfr[n], acc[m][n], 0, 0, 0);
    }

    // epilogue: C/D layout col = lane&15, row = (lane>>4)*4 + q
#pragma unroll
    for (int m = 0; m < 4; ++m) {
#pragma unroll
      for (int n = 0; n < 4; ++n) {
        const int vcol = bn * 128 + wc + n * 16 + l15g;
        const float bv = Why_b[vcol];
#pragma unroll
        for (int q = 0; q < 4; ++q) {
          const int trow = bm * 128 + wr + m * 16 + kc * 4 + q;
          C[(size_t)trow * VOCAB + vcol] = acc[m][n][q] + bv;
        }
      }
    }
    __syncthreads();  // all LDS reads done before next tile's staging
  }
}

extern "C" void kernel_launch(void* const* d_in, const int* in_sizes, int n_in,
                              void* d_out, int out_size, void* d_ws, size_t ws_size,
                              hipStream_t stream) {
  (void)in_sizes; (void)n_in; (void)out_size; (void)ws_size;

  const int*   idx   = (const int*)d_in[0];
  const float* h0    = (const float*)d_in[1];
  const float* Wxh_w = (const float*)d_in[2];
  const float* Wxh_b = (const float*)d_in[3];
  const float* Whh_w = (const float*)d_in[4];
  const float* Whh_b = (const float*)d_in[5];
  const float* Why_w = (const float*)d_in[6];
  const float* Why_b = (const float*)d_in[7];
  float* out = (float*)d_out;

  // workspace layout (bytes)
  char* ws = (char*)d_ws;
  float* pre = (float*)ws;                                   // 2,097,152
  __hip_bfloat16* h_bf = (__hip_bfloat16*)(ws + 2097152);    // (TSEQ+1)*512*2 = 1,049,600

  // sentinel-fill h rows 1..TSEQ (replay-safe: refilled every call)
  k_fill<<<(TSEQ * HIDDEN / 8 + 255) / 256, 256, 0, stream>>>(
      (uint4*)(h_bf + HIDDEN), TSEQ * HIDDEN / 8);
  k_pre<<<TSEQ, HIDDEN, 0, stream>>>(idx, h0, Wxh_w, Wxh_b, Whh_b, pre, h_bf);
  k_fused<<<NBLK, 256, 0, stream>>>(pre, Whh_w, h_bf, out + 32768000,
                                    Why_w, Why_b, out);
}